// Round 1
// baseline (509.577 us; speedup 1.0000x reference)
//
#include <hip/hip_runtime.h>
#include <hip/hip_bf16.h>

#define B_    2
#define S_    2048
#define H_    2048
#define NH_   16
#define NKV_  4
#define D_    128
#define WIN_  1024

typedef __attribute__((ext_vector_type(8))) short short8;
typedef __attribute__((ext_vector_type(4))) float f32x4;

__device__ __forceinline__ void gl2lds16(const void* g, void* l) {
  __builtin_amdgcn_global_load_lds(
      (const __attribute__((address_space(1))) void*)g,
      (__attribute__((address_space(3))) void*)l, 16, 0, 0);
}

__device__ __forceinline__ unsigned short f2bf(float x) {
  union { float f; unsigned int u; } v; v.f = x;
  unsigned int r = v.u + 0x7fffu + ((v.u >> 16) & 1u);
  return (unsigned short)(r >> 16);
}
__device__ __forceinline__ float bf2f(unsigned short u) {
  union { unsigned int i; float f; } v; v.i = ((unsigned int)u) << 16; return v.f;
}

// ---------------- fp32 -> bf16 convert (vectorized) ----------------
__global__ void convert_f32_bf16(const float* __restrict__ in,
                                 unsigned short* __restrict__ out, int n4) {
  int i = blockIdx.x * 256 + threadIdx.x;
  if (i < n4) {
    float4 v = ((const float4*)in)[i];
    ushort4 o;
    o.x = f2bf(v.x); o.y = f2bf(v.y); o.z = f2bf(v.z); o.w = f2bf(v.w);
    ((ushort4*)out)[i] = o;
  }
}

// ---------------- bf16 GEMM: C(MxN) = A(MxK) * B(NxK)^T ----------------
// 128x128 tile, BK=32, 256 threads (4 waves, each 64x64), global_load_lds(16B)
template <bool OUT_BF16>
__global__ __launch_bounds__(256) void gemm_bt(
    const unsigned short* __restrict__ A,
    const unsigned short* __restrict__ Bm,
    void* __restrict__ Cv, int M, int N, int K)
{
  __shared__ unsigned short As[128 * 32];
  __shared__ unsigned short Bs[128 * 32];
  const int t = threadIdx.x;
  const int lane = t & 63, wave = t >> 6;
  const int quad = lane >> 4, rl = lane & 15;
  const int bm = blockIdx.x * 128, bn = blockIdx.y * 128;
  const int wm = (wave >> 1) * 64, wn = (wave & 1) * 64;
  const int ldsbase = (t & ~63) * 8;

  f32x4 acc[4][4];
#pragma unroll
  for (int i = 0; i < 4; i++)
#pragma unroll
    for (int j = 0; j < 4; j++) acc[i][j] = (f32x4){0.f, 0.f, 0.f, 0.f};

  for (int k0 = 0; k0 < K; k0 += 32) {
#pragma unroll
    for (int i = 0; i < 2; i++) {
      int e = (i * 256 + t) * 8;
      int row = e >> 5, col = e & 31;
      gl2lds16(A + (long)(bm + row) * K + k0 + col, As + i * 2048 + ldsbase);
      gl2lds16(Bm + (long)(bn + row) * K + k0 + col, Bs + i * 2048 + ldsbase);
    }
    __syncthreads();
    short8 af[4], bfr[4];
#pragma unroll
    for (int i = 0; i < 4; i++)
      af[i] = *(const short8*)(As + (wm + i * 16 + rl) * 32 + quad * 8);
#pragma unroll
    for (int j = 0; j < 4; j++)
      bfr[j] = *(const short8*)(Bs + (wn + j * 16 + rl) * 32 + quad * 8);
#pragma unroll
    for (int i = 0; i < 4; i++)
#pragma unroll
      for (int j = 0; j < 4; j++)
        acc[i][j] = __builtin_amdgcn_mfma_f32_16x16x32_bf16(af[i], bfr[j], acc[i][j], 0, 0, 0);
    __syncthreads();
  }
  // C/D layout: col = lane&15, row = quad*4 + reg  [verified m89/m91]
#pragma unroll
  for (int i = 0; i < 4; i++) {
    int row0 = bm + wm + i * 16 + quad * 4;
#pragma unroll
    for (int j = 0; j < 4; j++) {
      int col = bn + wn + j * 16 + rl;
#pragma unroll
      for (int r = 0; r < 4; r++) {
        if (OUT_BF16)
          ((unsigned short*)Cv)[(long)(row0 + r) * N + col] = f2bf(acc[i][j][r]);
        else
          ((float*)Cv)[(long)(row0 + r) * N + col] = acc[i][j][r];
      }
    }
  }
}

// ---------------- RMSNorm + RoPE + pack ----------------
// qkvg: bf16 [4096, 5120] (q 0:2048 | k 2048:2560 | v 2560:3072 | gate 3072:5120)
// out: qb [B,NH,S,D] bf16, kb [B,NKV,S,D] bf16, vt [B,NKV,D,S] bf16 (V transposed)
__global__ __launch_bounds__(256) void pack_norm_rope(
    const unsigned short* __restrict__ qkvg,
    const float* __restrict__ cosb, const float* __restrict__ sinb,
    const float* __restrict__ qw, const float* __restrict__ kw,
    unsigned short* __restrict__ qb, unsigned short* __restrict__ kb,
    unsigned short* __restrict__ vt)
{
  int t = threadIdx.x, lane = t & 63, wave = t >> 6;
  long gw = (long)blockIdx.x * 4 + wave;       // 0 .. B*S*24-1
  int hu = (int)(gw % 24);
  long bs = gw / 24;                           // b*S + s
  int s = (int)(bs % S_);
  int b = (int)(bs / S_);
  const unsigned short* row = qkvg + bs * 5120;

  if (hu >= 20) {                              // V: transpose copy
    int kvh = hu - 20;
    const unsigned short* base = row + 2560 + kvh * 128;
    long o = (long)(b * NKV_ + kvh) * 128;
    vt[(o + lane) * S_ + s] = base[lane];
    vt[(o + lane + 64) * S_ + s] = base[lane + 64];
    return;
  }
  bool isq = hu < 16;
  const unsigned short* base = isq ? (row + hu * 128) : (row + 2048 + (hu - 16) * 128);
  float x1 = bf2f(base[lane]), x2 = bf2f(base[lane + 64]);
  float ss = x1 * x1 + x2 * x2;
#pragma unroll
  for (int m = 1; m < 64; m <<= 1) ss += __shfl_xor(ss, m, 64);
  float inv = rsqrtf(ss * (1.0f / 128.0f) + 1e-5f);
  const float* w = isq ? qw : kw;
  float n1 = x1 * inv * w[lane], n2 = x2 * inv * w[lane + 64];
  const float* cp = cosb + bs * 128;
  const float* sp = sinb + bs * 128;
  float o1 = n1 * cp[lane] - n2 * sp[lane];          // d < 64:  x*c - x2*s
  float o2 = n2 * cp[lane + 64] + n1 * sp[lane + 64]; // d >= 64: x*c + x1*s
  if (isq) {
    long o = ((long)(b * NH_ + hu) * S_ + s) * 128;
    qb[o + lane] = f2bf(o1); qb[o + lane + 64] = f2bf(o2);
  } else {
    long o = ((long)(b * NKV_ + (hu - 16)) * S_ + s) * 128;
    kb[o + lane] = f2bf(o1); kb[o + lane + 64] = f2bf(o2);
  }
}

// ---------------- flash attention, sliding window, fused gate ----------------
// block = 256 thr (4 waves), one block per (b, h, 64-row q tile)
// wave w owns q rows [q0+16w, q0+16w+16)
__global__ __launch_bounds__(256) void attn_kernel(
    const unsigned short* __restrict__ qb,   // [B,NH,S,D]
    const unsigned short* __restrict__ kbuf, // [B,NKV,S,D]
    const unsigned short* __restrict__ vt,   // [B,NKV,D,S]
    const unsigned short* __restrict__ qkvg, // gate at col 3072+
    unsigned short* __restrict__ aout)       // [B,S,NH*D] bf16
{
  __shared__ unsigned short Ks[64 * 128];   // K tile, row-major (key, d)
  __shared__ unsigned short Vs[128 * 64];   // V^T tile, row-major (d, key)
  __shared__ unsigned short Ps[4][16 * 64]; // per-wave P in A-operand feed layout
  int t = threadIdx.x, lane = t & 63, wave = t >> 6;
  int quad = lane >> 4, rl = lane & 15;
  int blk = blockIdx.x;
  int qt = blk & 31, h = (blk >> 5) & 15, b = blk >> 9;
  int kv = h >> 2;                           // GROUPS = 4
  int q0 = qt * 64;

  // Q fragments (A-operand: A[m=lane&15][k=quad*8+j]) straight from global
  const unsigned short* qrow =
      qb + (((long)(b * NH_ + h)) * S_ + q0 + wave * 16 + rl) * 128;
  short8 qf[4];
#pragma unroll
  for (int ks = 0; ks < 4; ks++) qf[ks] = *(const short8*)(qrow + ks * 32 + quad * 8);

  f32x4 oacc[8];
#pragma unroll
  for (int j = 0; j < 8; j++) oacc[j] = (f32x4){0.f, 0.f, 0.f, 0.f};
  float m_r[4] = {-1e9f, -1e9f, -1e9f, -1e9f};
  float l_r[4] = {0.f, 0.f, 0.f, 0.f};

  const unsigned short* kbase_p = kbuf + ((long)(b * NKV_ + kv)) * S_ * 128;
  const unsigned short* vbase_p = vt + ((long)(b * NKV_ + kv)) * 128 * S_;
  int ldsb = (t & ~63) * 8;
  int t_lo = qt - 16; if (t_lo < 0) t_lo = 0;

  for (int kt = t_lo; kt <= qt; ++kt) {
    int kb0 = kt * 64;
#pragma unroll
    for (int i = 0; i < 4; i++) {
      int e = (i * 256 + t) * 8;
      { int r2 = e >> 7, c2 = e & 127;
        gl2lds16(kbase_p + (long)(kb0 + r2) * 128 + c2, Ks + i * 2048 + ldsb); }
      { int r2 = e >> 6, c2 = e & 63;
        gl2lds16(vbase_p + (long)r2 * S_ + kb0 + c2, Vs + i * 2048 + ldsb); }
    }
    __syncthreads();

    // S = Q K^T  (16 q-rows x 64 keys per wave)
    f32x4 sc[4];
#pragma unroll
    for (int nt = 0; nt < 4; nt++) {
      f32x4 c = (f32x4){0.f, 0.f, 0.f, 0.f};
#pragma unroll
      for (int ks = 0; ks < 4; ks++) {
        short8 bfrag = *(const short8*)(Ks + (nt * 16 + rl) * 128 + ks * 32 + quad * 8);
        c = __builtin_amdgcn_mfma_f32_16x16x32_bf16(qf[ks], bfrag, c, 0, 0, 0);
      }
      sc[nt] = c;
    }
    const float scale = 0.08838834764831845f;  // 1/sqrt(128)
#pragma unroll
    for (int nt = 0; nt < 4; nt++)
#pragma unroll
      for (int r = 0; r < 4; r++) {
        int i_row = q0 + wave * 16 + quad * 4 + r;
        int j_col = kb0 + nt * 16 + rl;
        bool ok = (j_col <= i_row) && (i_row - j_col < WIN_);
        sc[nt][r] = ok ? sc[nt][r] * scale : -1e9f;
      }
    // online softmax (rows quad*4+r live in the 16 lanes of the quad)
#pragma unroll
    for (int r = 0; r < 4; r++) {
      float mx = fmaxf(fmaxf(sc[0][r], sc[1][r]), fmaxf(sc[2][r], sc[3][r]));
#pragma unroll
      for (int m = 1; m < 16; m <<= 1) mx = fmaxf(mx, __shfl_xor(mx, m, 64));
      float newm = fmaxf(m_r[r], mx);
      float alpha = __expf(m_r[r] - newm);
      float p0 = __expf(sc[0][r] - newm), p1 = __expf(sc[1][r] - newm);
      float p2 = __expf(sc[2][r] - newm), p3 = __expf(sc[3][r] - newm);
      float rs = p0 + p1 + p2 + p3;
#pragma unroll
      for (int m = 1; m < 16; m <<= 1) rs += __shfl_xor(rs, m, 64);
      l_r[r] = l_r[r] * alpha + rs;
      m_r[r] = newm;
#pragma unroll
      for (int j = 0; j < 8; j++) oacc[j][r] *= alpha;
      int prow = (quad * 4 + r) * 64;
      Ps[wave][prow + 0 * 16 + rl] = f2bf(p0);
      Ps[wave][prow + 1 * 16 + rl] = f2bf(p1);
      Ps[wave][prow + 2 * 16 + rl] = f2bf(p2);
      Ps[wave][prow + 3 * 16 + rl] = f2bf(p3);
    }
    __syncthreads();  // P visible (and safe vs. other waves)

    // O += P V   (P: A-layout from LDS; V^T: B-operand rows contiguous)
#pragma unroll
    for (int ks2 = 0; ks2 < 2; ks2++) {
      short8 af2 = *(const short8*)(&Ps[wave][rl * 64 + ks2 * 32 + quad * 8]);
#pragma unroll
      for (int j = 0; j < 8; j++) {
        short8 bf2 = *(const short8*)(Vs + (j * 16 + rl) * 64 + ks2 * 32 + quad * 8);
        oacc[j] = __builtin_amdgcn_mfma_f32_16x16x32_bf16(af2, bf2, oacc[j], 0, 0, 0);
      }
    }
    __syncthreads();  // all reads done before next tile's staging
  }

  // epilogue: /l, * sigmoid(gate), write bf16 [B,S,NH*D]
#pragma unroll
  for (int r = 0; r < 4; r++) {
    int s_idx = q0 + wave * 16 + quad * 4 + r;
    float invl = 1.0f / l_r[r];
    long rowoff = (long)(b * S_ + s_idx);
    const unsigned short* grow = qkvg + rowoff * 5120 + 3072 + h * 128;
    unsigned short* orow = aout + rowoff * 2048 + h * 128;
#pragma unroll
    for (int j = 0; j < 8; j++) {
      int d = j * 16 + rl;
      float o = oacc[j][r] * invl;
      float g = bf2f(grow[d]);
      o = o / (1.0f + __expf(-g));
      orow[d] = f2bf(o);
    }
  }
}

extern "C" void kernel_launch(void* const* d_in, const int* in_sizes, int n_in,
                              void* d_out, int out_size, void* d_ws, size_t ws_size,
                              hipStream_t stream) {
  (void)in_sizes; (void)n_in; (void)out_size; (void)ws_size;
  const float* hs   = (const float*)d_in[0];
  const float* cosb = (const float*)d_in[1];
  const float* sinb = (const float*)d_in[2];
  // d_in[3] = attention_mask: analytic (causal sliding window), not read
  const float* Wq = (const float*)d_in[4];
  const float* Wk = (const float*)d_in[5];
  const float* Wv = (const float*)d_in[6];
  const float* Wo = (const float*)d_in[7];
  const float* Wg = (const float*)d_in[8];
  const float* qw = (const float*)d_in[9];
  const float* kw = (const float*)d_in[10];
  float* out = (float*)d_out;

  char* ws = (char*)d_ws;
  unsigned short* Xb   = (unsigned short*)ws; ws += (size_t)4096 * 2048 * 2;
  unsigned short* Wall = (unsigned short*)ws; ws += (size_t)5120 * 2048 * 2;
  unsigned short* Wob  = (unsigned short*)ws; ws += (size_t)2048 * 2048 * 2;
  unsigned short* qkvg = (unsigned short*)ws; ws += (size_t)4096 * 5120 * 2;
  unsigned short* qb   = (unsigned short*)ws; ws += (size_t)B_ * NH_ * S_ * D_ * 2;
  unsigned short* kbuf = (unsigned short*)ws; ws += (size_t)B_ * NKV_ * S_ * D_ * 2;
  unsigned short* vtb  = (unsigned short*)ws; ws += (size_t)B_ * NKV_ * S_ * D_ * 2;
  unsigned short* aout = (unsigned short*)ws; ws += (size_t)4096 * 2048 * 2;

  auto cvt = [&](const float* src, unsigned short* dst, long n) {
    int n4 = (int)(n / 4);
    convert_f32_bf16<<<(n4 + 255) / 256, 256, 0, stream>>>(src, dst, n4);
  };
  cvt(hs, Xb, (long)4096 * 2048);
  cvt(Wq, Wall, (long)2048 * 2048);
  cvt(Wk, Wall + (size_t)2048 * 2048, (long)512 * 2048);
  cvt(Wv, Wall + (size_t)2560 * 2048, (long)512 * 2048);
  cvt(Wg, Wall + (size_t)3072 * 2048, (long)2048 * 2048);
  cvt(Wo, Wob, (long)2048 * 2048);

  gemm_bt<true><<<dim3(32, 40), 256, 0, stream>>>(Xb, Wall, (void*)qkvg, 4096, 5120, 2048);
  pack_norm_rope<<<24576, 256, 0, stream>>>(qkvg, cosb, sinb, qw, kw, qb, kbuf, vtb);
  attn_kernel<<<1024, 256, 0, stream>>>(qb, kbuf, vtb, qkvg, aout);
  gemm_bt<false><<<dim3(32, 16), 256, 0, stream>>>(aout, Wob, (void*)out, 4096, 2048, 2048);
}